// Round 1
// baseline (98.673 us; speedup 1.0000x reference)
//
#include <hip/hip_runtime.h>
#include <hip/hip_bf16.h>

// Chamfer loss, B=8, N=M=8192, D=3, fp32.
// loss_1 = mean over preds of min over gts dist^2  (queries=preds, refs=gts)
// loss_2 = mean over gts  of min over preds dist^2 (queries=gts, refs=preds)
// out[0] = loss_1 + loss_2 = (sum of all 131072 per-query mins) / 65536.
//
// Trick: d(q,r) = |q|^2 + |r|^2 - 2 q.r. Track g = 0.5|r|^2 - q.r per pair
// (3 fma + 1 min with -q pre-negated and 0.5|r|^2 staged as the LDS float4.w),
// then d_min = 2*g_min + |q|^2 once per query.

#define NPTS 8192
#define BATCH 8
#define TPB 256
#define QPT 4          // queries per thread
#define NSLICE 4       // ref slices per (dir,b)
#define REFS_PER_SLICE (NPTS / NSLICE)   // 2048
#define QPB (TPB * QPT)                  // 1024 queries per block
#define QBLKS (NPTS / QPB)               // 8

__global__ __launch_bounds__(TPB, 2) void chamfer_min_kernel(
    const float* __restrict__ preds, const float* __restrict__ gts,
    float* __restrict__ partial /* [2][BATCH][NPTS][NSLICE] */)
{
    __shared__ float4 lds[REFS_PER_SLICE];   // 32 KB

    const int bid = blockIdx.x;      // 512 blocks
    const int dir = bid >> 8;        // 256 blocks per direction
    const int rem = bid & 255;
    const int b   = rem >> 5;        // 8 batches
    const int sub = rem & 31;
    const int qblk = sub >> 2;       // 8 query blocks
    const int s    = sub & 3;        // 4 ref slices

    const float* __restrict__ qsrc = (dir == 0) ? preds : gts;
    const float* __restrict__ rsrc = (dir == 0) ? gts : preds;
    const float* __restrict__ qb = qsrc + (size_t)b * NPTS * 3;
    const float* __restrict__ rb = rsrc + ((size_t)b * NPTS + (size_t)s * REFS_PER_SLICE) * 3;

    const int tid = threadIdx.x;

    // Stage ref slice into LDS as (x, y, z, 0.5*|r|^2)
    for (int p = tid; p < REFS_PER_SLICE; p += TPB) {
        float x = rb[p * 3 + 0];
        float y = rb[p * 3 + 1];
        float z = rb[p * 3 + 2];
        lds[p] = make_float4(x, y, z, 0.5f * (x * x + y * y + z * z));
    }

    // Load this thread's 4 queries into registers (negated)
    float nqx[QPT], nqy[QPT], nqz[QPT], qq[QPT], best[QPT];
#pragma unroll
    for (int i = 0; i < QPT; ++i) {
        int q = qblk * QPB + i * TPB + tid;
        float x = qb[q * 3 + 0];
        float y = qb[q * 3 + 1];
        float z = qb[q * 3 + 2];
        nqx[i] = -x; nqy[i] = -y; nqz[i] = -z;
        qq[i] = x * x + y * y + z * z;
        best[i] = 1e30f;
    }

    __syncthreads();

#pragma unroll 4
    for (int j = 0; j < REFS_PER_SLICE; ++j) {
        float4 r = lds[j];
#pragma unroll
        for (int i = 0; i < QPT; ++i) {
            float g = fmaf(nqx[i], r.x, r.w);
            g = fmaf(nqy[i], r.y, g);
            g = fmaf(nqz[i], r.z, g);
            best[i] = fminf(best[i], g);
        }
    }

    // partial min of true squared distance for this slice
#pragma unroll
    for (int i = 0; i < QPT; ++i) {
        int q = qblk * QPB + i * TPB + tid;
        size_t idx = ((((size_t)dir * BATCH + b) * NPTS) + q) * NSLICE + s;
        partial[idx] = fmaf(2.0f, best[i], qq[i]);
    }
}

// Stage 2: min over the 4 slices per query, sum within block -> bsums[512]
__global__ __launch_bounds__(256) void chamfer_reduce1(
    const float* __restrict__ partial, float* __restrict__ bsums)
{
    const int gid = blockIdx.x * 256 + threadIdx.x;   // [0, 131072)
    const float4* __restrict__ p4 = (const float4*)partial;
    float4 v = p4[gid];
    float m = fminf(fminf(v.x, v.y), fminf(v.z, v.w));

#pragma unroll
    for (int off = 32; off > 0; off >>= 1) m += __shfl_down(m, off, 64);

    __shared__ float wsum[4];
    const int lane = threadIdx.x & 63;
    const int wid  = threadIdx.x >> 6;
    if (lane == 0) wsum[wid] = m;
    __syncthreads();
    if (threadIdx.x == 0)
        bsums[blockIdx.x] = (wsum[0] + wsum[1]) + (wsum[2] + wsum[3]);
}

// Stage 3: sum 512 block sums, scale, write scalar
__global__ __launch_bounds__(512) void chamfer_reduce2(
    const float* __restrict__ bsums, float* __restrict__ out)
{
    float m = bsums[threadIdx.x];
#pragma unroll
    for (int off = 32; off > 0; off >>= 1) m += __shfl_down(m, off, 64);

    __shared__ float wsum[8];
    const int lane = threadIdx.x & 63;
    const int wid  = threadIdx.x >> 6;
    if (lane == 0) wsum[wid] = m;
    __syncthreads();
    if (threadIdx.x == 0) {
        float t = ((wsum[0] + wsum[1]) + (wsum[2] + wsum[3]))
                + ((wsum[4] + wsum[5]) + (wsum[6] + wsum[7]));
        out[0] = t * (1.0f / 65536.0f);
    }
}

extern "C" void kernel_launch(void* const* d_in, const int* in_sizes, int n_in,
                              void* d_out, int out_size, void* d_ws, size_t ws_size,
                              hipStream_t stream) {
    const float* preds = (const float*)d_in[0];   // [8, 8192, 3]
    const float* gts   = (const float*)d_in[1];   // [8, 8192, 3]
    float* out = (float*)d_out;

    float* partial = (float*)d_ws;                                 // 2*8*8192*4 floats = 2 MB
    float* bsums   = (float*)((char*)d_ws + (size_t)2 * BATCH * NPTS * NSLICE * sizeof(float));

    chamfer_min_kernel<<<512, TPB, 0, stream>>>(preds, gts, partial);
    chamfer_reduce1<<<512, 256, 0, stream>>>(partial, bsums);
    chamfer_reduce2<<<1, 512, 0, stream>>>(bsums, out);
}

// Round 2
// 95.352 us; speedup vs baseline: 1.0348x; 1.0348x over previous
//
#include <hip/hip_runtime.h>
#include <hip/hip_bf16.h>

// Chamfer loss, B=8, N=M=8192, D=3, fp32.
// dir 0: queries=preds, refs=gts (loss_1 terms); dir 1: queries=gts, refs=preds.
// out[0] = (sum of all 131072 per-query min squared distances) / 65536.
//
// Per-pair math: d = |q|^2 + |r|^2 - 2 q.r. Track g = 0.5|r|^2 - q.r
// (with -q pre-negated, 0.5|r|^2 staged alongside the ref), then
// d_min = 2*g_min + |q|^2 once per query.
//
// Packed fp32: refs processed two-at-a-time via v_pk_fma_f32 (VOP3P).
// LDS stores ref PAIRS pre-transposed: ldsA={x0,x1,y0,y1}, ldsB={z0,z1,w0,w1},
// so ds_read_b128 delivers each packed operand as an aligned VGPR pair.
// Per 2 refs per query: 3 pk_fma + 2 v_min = 2.5 issue slots/pair (vs 4 scalar).

typedef float f32x2 __attribute__((ext_vector_type(2)));
typedef float f32x4 __attribute__((ext_vector_type(4)));

#define NPTS 8192
#define BATCH 8
#define TPB 256
#define QPT 8                      // queries per thread
#define NSLICE 16                  // ref slices per (dir,b)
#define RPS (NPTS / NSLICE)        // 512 refs per slice
#define PAIRS (RPS / 2)            // 256 ref-pairs per slice
#define QPB (TPB * QPT)            // 2048 queries per block
#define QBLKS (NPTS / QPB)         // 4
#define NQ_TOT (2 * BATCH * NPTS)  // 131072 total queries

__device__ __forceinline__ f32x2 pk_fma(f32x2 a, f32x2 b, f32x2 c) {
    f32x2 d;
    asm("v_pk_fma_f32 %0, %1, %2, %3" : "=v"(d) : "v"(a), "v"(b), "v"(c));
    return d;
}

__global__ __launch_bounds__(TPB, 4) void chamfer_min_kernel(
    const float* __restrict__ preds, const float* __restrict__ gts,
    float* __restrict__ minarr /* [2][BATCH][NPTS], int-min'd */)
{
    __shared__ f32x4 ldsA[PAIRS];   // {x0,x1,y0,y1}
    __shared__ f32x4 ldsB[PAIRS];   // {z0,z1,w0,w1}  w = 0.5*|r|^2

    const int bid = blockIdx.x;     // 1024 blocks
    const int dir = bid >> 9;
    const int rem = bid & 511;
    const int b   = rem >> 6;       // 8 batches
    const int sub = rem & 63;
    const int qblk = sub >> 4;      // 4 query blocks
    const int s    = sub & 15;      // 16 ref slices

    const float* __restrict__ qsrc = (dir == 0) ? preds : gts;
    const float* __restrict__ rsrc = (dir == 0) ? gts : preds;
    const float* __restrict__ qb = qsrc + (size_t)b * NPTS * 3;
    const float* __restrict__ rb = rsrc + ((size_t)b * NPTS + (size_t)s * RPS) * 3;

    const int tid = threadIdx.x;

    // Stage one ref pair per thread (PAIRS == TPB), pre-transposed.
    {
        const float* rp = rb + tid * 6;
        float x0 = rp[0], y0 = rp[1], z0 = rp[2];
        float x1 = rp[3], y1 = rp[4], z1 = rp[5];
        float w0 = 0.5f * (x0 * x0 + y0 * y0 + z0 * z0);
        float w1 = 0.5f * (x1 * x1 + y1 * y1 + z1 * z1);
        ldsA[tid] = f32x4{x0, x1, y0, y1};
        ldsB[tid] = f32x4{z0, z1, w0, w1};
    }

    // This thread's 8 queries, negated, duplicated into both packed halves.
    f32x2 nqx[QPT], nqy[QPT], nqz[QPT], best[QPT];
    float qq[QPT];
#pragma unroll
    for (int i = 0; i < QPT; ++i) {
        int q = qblk * QPB + i * TPB + tid;
        float x = qb[q * 3 + 0];
        float y = qb[q * 3 + 1];
        float z = qb[q * 3 + 2];
        nqx[i] = f32x2{-x, -x};
        nqy[i] = f32x2{-y, -y};
        nqz[i] = f32x2{-z, -z};
        qq[i] = x * x + y * y + z * z;
        best[i] = f32x2{1e30f, 1e30f};
    }

    __syncthreads();

#pragma unroll 2
    for (int p = 0; p < PAIRS; ++p) {
        f32x4 A = ldsA[p];
        f32x4 B = ldsB[p];
        f32x2 rx = __builtin_shufflevector(A, A, 0, 1);
        f32x2 ry = __builtin_shufflevector(A, A, 2, 3);
        f32x2 rz = __builtin_shufflevector(B, B, 0, 1);
        f32x2 rw = __builtin_shufflevector(B, B, 2, 3);
#pragma unroll
        for (int i = 0; i < QPT; ++i) {
            f32x2 g = pk_fma(nqx[i], rx, rw);
            g = pk_fma(nqy[i], ry, g);
            g = pk_fma(nqz[i], rz, g);
            best[i].x = fminf(best[i].x, g.x);
            best[i].y = fminf(best[i].y, g.y);
        }
    }

    // Fold slice-local min into the global per-query min.
    // d2 >= 0 (mathematically), so int-compare == float-compare for atomicMin.
#pragma unroll
    for (int i = 0; i < QPT; ++i) {
        int q = qblk * QPB + i * TPB + tid;
        float gm = fminf(best[i].x, best[i].y);
        float d2 = fmaf(2.0f, gm, qq[i]);
        atomicMin((int*)&minarr[((size_t)dir * BATCH + b) * NPTS + q],
                  __float_as_int(d2));
    }
}

// Stage 2: sum 131072 mins -> 512 block sums
__global__ __launch_bounds__(256) void chamfer_reduce1(
    const float* __restrict__ minarr, float* __restrict__ bsums)
{
    const int gid = blockIdx.x * 256 + threadIdx.x;
    float m = minarr[gid];

#pragma unroll
    for (int off = 32; off > 0; off >>= 1) m += __shfl_down(m, off, 64);

    __shared__ float wsum[4];
    const int lane = threadIdx.x & 63;
    const int wid  = threadIdx.x >> 6;
    if (lane == 0) wsum[wid] = m;
    __syncthreads();
    if (threadIdx.x == 0)
        bsums[blockIdx.x] = (wsum[0] + wsum[1]) + (wsum[2] + wsum[3]);
}

// Stage 3: sum 512 block sums, scale, write scalar
__global__ __launch_bounds__(512) void chamfer_reduce2(
    const float* __restrict__ bsums, float* __restrict__ out)
{
    float m = bsums[threadIdx.x];
#pragma unroll
    for (int off = 32; off > 0; off >>= 1) m += __shfl_down(m, off, 64);

    __shared__ float wsum[8];
    const int lane = threadIdx.x & 63;
    const int wid  = threadIdx.x >> 6;
    if (lane == 0) wsum[wid] = m;
    __syncthreads();
    if (threadIdx.x == 0) {
        float t = ((wsum[0] + wsum[1]) + (wsum[2] + wsum[3]))
                + ((wsum[4] + wsum[5]) + (wsum[6] + wsum[7]));
        out[0] = t * (1.0f / 65536.0f);
    }
}

extern "C" void kernel_launch(void* const* d_in, const int* in_sizes, int n_in,
                              void* d_out, int out_size, void* d_ws, size_t ws_size,
                              hipStream_t stream) {
    const float* preds = (const float*)d_in[0];   // [8, 8192, 3]
    const float* gts   = (const float*)d_in[1];   // [8, 8192, 3]
    float* out = (float*)d_out;

    float* minarr = (float*)d_ws;                          // 131072 floats = 512 KB
    float* bsums  = (float*)((char*)d_ws + (size_t)NQ_TOT * sizeof(float));  // +2 KB

    // 0x7f7f7f7f == 3.39e38f: "+inf" init for the int-cast atomicMin.
    hipMemsetAsync(minarr, 0x7f, (size_t)NQ_TOT * sizeof(float), stream);

    chamfer_min_kernel<<<1024, TPB, 0, stream>>>(preds, gts, minarr);
    chamfer_reduce1<<<512, 256, 0, stream>>>(minarr, bsums);
    chamfer_reduce2<<<1, 512, 0, stream>>>(bsums, out);
}

// Round 3
// 47.771 us; speedup vs baseline: 2.0656x; 1.9960x over previous
//
#include <hip/hip_runtime.h>
#include <hip/hip_bf16.h>

// Chamfer via MFMA: D_nm = |x_n - y_m|^2 as an augmented K=16 fp16-split GEMM.
//   a(x) = [xh0..2, xl0..2, xh0..2, 1, 1, xxh, xxl, 0,0,0]
//   b(y) = [-2yh0..2, -2yh0..2, -2yl0..2, yyh, yyl, 1, 1, 0,0,0]
//   sum_k a_k b_k = xx + yy - 2(xh+xl).(yh+yl)  (drops xl.yl ~3e-5)
// One v_mfma_f32_32x32x16_f16 = one 32x32 distance tile, fp32 accum.
// Two passes (A=gts,B=preds then swapped): only ROW-mins needed -> no atomics.
// out = (sum of 131072 row-mins) / 65536.

typedef _Float16 f16x8 __attribute__((ext_vector_type(8)));
typedef float f32x16 __attribute__((ext_vector_type(16)));

#define NPTS 8192
#define BATCH 8
#define TPB 256
#define BN 256                      // rows per block (4 waves x 2 rowtiles x 32)
#define BM 1024                     // cols staged per LDS chunk
#define NCHUNK (NPTS / BM)          // 8
#define CTPC (BM / 32)              // 32 col-tiles per chunk

__device__ __forceinline__ void cvt_split(float v, _Float16& h, _Float16& l) {
    h = (_Float16)v;
    l = (_Float16)(v - (float)h);
}

__global__ __launch_bounds__(TPB, 2) void chamfer_mfma_kernel(
    const float* __restrict__ preds, const float* __restrict__ gts,
    float* __restrict__ rowmin /* [2][BATCH][NPTS] */)
{
    __shared__ f16x8 ldsB[CTPC][2][32];   // 32 KB: [coltile][khalf][col]

    const int bid  = blockIdx.x;      // 512 blocks
    const int pass = bid >> 8;        // 0: rows=gts cols=preds; 1: swapped
    const int rem  = bid & 255;
    const int b      = rem >> 5;      // 8 batches
    const int rowblk = rem & 31;      // 32 row-blocks (8192/256)

    const float* __restrict__ Asrc = (pass == 0) ? gts : preds;
    const float* __restrict__ Bsrc = (pass == 0) ? preds : gts;
    const float* __restrict__ Ab = Asrc + (size_t)b * NPTS * 3;
    const float* __restrict__ Bb = Bsrc + (size_t)b * NPTS * 3;

    const int tid  = threadIdx.x;
    const int lane = tid & 63;
    const int w    = tid >> 6;        // wave id, 4 waves
    const int kh   = lane >> 5;       // k-half for A/B fragments
    const int cl   = lane & 31;       // row (A) / col (B) within tile

    // --- A fragments (2 row-tiles per wave), converted in-register ---
    f16x8 af[2];
#pragma unroll
    for (int t = 0; t < 2; ++t) {
        const int row = rowblk * BN + w * 64 + t * 32 + cl;
        const float* xp = Ab + (size_t)row * 3;
        const float x0 = xp[0], x1 = xp[1], x2 = xp[2];
        _Float16 h0, l0, h1, l1, h2, l2;
        cvt_split(x0, h0, l0); cvt_split(x1, h1, l1); cvt_split(x2, h2, l2);
        const float xx = x0 * x0 + x1 * x1 + x2 * x2;
        _Float16 xxh, xxl; cvt_split(xx, xxh, xxl);
        const f16x8 lo = { h0, h1, h2, l0, l1, l2, h0, h1 };
        const f16x8 hi = { h2, (_Float16)1, (_Float16)1, xxh, xxl,
                           (_Float16)0, (_Float16)0, (_Float16)0 };
        af[t] = kh ? hi : lo;
    }

    const f16x8* __restrict__ bptr = &ldsB[0][kh][cl];   // + ct*64 elems per tile
    const f32x16 zc = {};                                // persistent zero C

    float rb[2][16];
#pragma unroll
    for (int t = 0; t < 2; ++t)
#pragma unroll
        for (int r = 0; r < 16; ++r) rb[t][r] = 1e30f;

    for (int chunk = 0; chunk < NCHUNK; ++chunk) {
        __syncthreads();   // previous chunk's reads done before overwrite
        // --- stage+convert BM cols into LDS (4 points per thread) ---
#pragma unroll
        for (int i = 0; i < BM / TPB; ++i) {
            const int pl = i * TPB + tid;                 // 0..BM-1
            const float* yp = Bb + (size_t)(chunk * BM + pl) * 3;
            const float y0 = yp[0], y1 = yp[1], y2 = yp[2];
            _Float16 nh0, nl0, nh1, nl1, nh2, nl2;
            { const float hf = (float)(_Float16)y0; nh0 = (_Float16)(-2.f * hf); nl0 = (_Float16)(-2.f * (y0 - hf)); }
            { const float hf = (float)(_Float16)y1; nh1 = (_Float16)(-2.f * hf); nl1 = (_Float16)(-2.f * (y1 - hf)); }
            { const float hf = (float)(_Float16)y2; nh2 = (_Float16)(-2.f * hf); nl2 = (_Float16)(-2.f * (y2 - hf)); }
            const float yy = y0 * y0 + y1 * y1 + y2 * y2;
            _Float16 yyh, yyl; cvt_split(yy, yyh, yyl);
            const f16x8 lo = { nh0, nh1, nh2, nh0, nh1, nh2, nl0, nl1 };
            const f16x8 hi = { nl2, yyh, yyl, (_Float16)1, (_Float16)1,
                               (_Float16)0, (_Float16)0, (_Float16)0 };
            ldsB[pl >> 5][0][pl & 31] = lo;
            ldsB[pl >> 5][1][pl & 31] = hi;
        }
        __syncthreads();

        // --- sweep col-tiles: 1 ds_read_b128 -> 2 MFMA -> 32 v_min ---
#pragma unroll 4
        for (int ct = 0; ct < CTPC; ++ct) {
            const f16x8 bf = bptr[ct * 64];
            const f32x16 a0 = __builtin_amdgcn_mfma_f32_32x32x16_f16(af[0], bf, zc, 0, 0, 0);
            const f32x16 a1 = __builtin_amdgcn_mfma_f32_32x32x16_f16(af[1], bf, zc, 0, 0, 0);
#pragma unroll
            for (int r = 0; r < 16; ++r) rb[0][r] = fminf(rb[0][r], a0[r]);
#pragma unroll
            for (int r = 0; r < 16; ++r) rb[1][r] = fminf(rb[1][r], a1[r]);
        }
    }

    // --- reduce row-mins across the 32 cols (lane bits 0..4) ---
#pragma unroll
    for (int t = 0; t < 2; ++t)
#pragma unroll
        for (int r = 0; r < 16; ++r) {
            float v = rb[t][r];
            v = fminf(v, __shfl_xor(v, 1, 64));
            v = fminf(v, __shfl_xor(v, 2, 64));
            v = fminf(v, __shfl_xor(v, 4, 64));
            v = fminf(v, __shfl_xor(v, 8, 64));
            v = fminf(v, __shfl_xor(v, 16, 64));
            rb[t][r] = v;
        }

    // C layout (verified m74/m101): col=lane&31, row=(r&3)+8*(r>>2)+4*(lane>>5)
    if (cl == 0) {
        float* rbase = rowmin + ((size_t)(pass * BATCH + b) * NPTS)
                     + rowblk * BN + w * 64;
#pragma unroll
        for (int t = 0; t < 2; ++t)
#pragma unroll
            for (int r = 0; r < 16; ++r) {
                const int rloc = (r & 3) + 8 * (r >> 2) + 4 * kh;
                rbase[t * 32 + rloc] = rb[t][r];
            }
    }
}

// Stage 2: sum 131072 row-mins -> 512 block sums
__global__ __launch_bounds__(256) void chamfer_reduce1(
    const float* __restrict__ rowmin, float* __restrict__ bsums)
{
    const int gid = blockIdx.x * 256 + threadIdx.x;
    float m = rowmin[gid];
#pragma unroll
    for (int off = 32; off > 0; off >>= 1) m += __shfl_down(m, off, 64);

    __shared__ float wsum[4];
    const int lane = threadIdx.x & 63;
    const int wid  = threadIdx.x >> 6;
    if (lane == 0) wsum[wid] = m;
    __syncthreads();
    if (threadIdx.x == 0)
        bsums[blockIdx.x] = (wsum[0] + wsum[1]) + (wsum[2] + wsum[3]);
}

// Stage 3: sum 512 block sums, scale, write scalar
__global__ __launch_bounds__(512) void chamfer_reduce2(
    const float* __restrict__ bsums, float* __restrict__ out)
{
    float m = bsums[threadIdx.x];
#pragma unroll
    for (int off = 32; off > 0; off >>= 1) m += __shfl_down(m, off, 64);

    __shared__ float wsum[8];
    const int lane = threadIdx.x & 63;
    const int wid  = threadIdx.x >> 6;
    if (lane == 0) wsum[wid] = m;
    __syncthreads();
    if (threadIdx.x == 0) {
        float t = ((wsum[0] + wsum[1]) + (wsum[2] + wsum[3]))
                + ((wsum[4] + wsum[5]) + (wsum[6] + wsum[7]));
        out[0] = t * (1.0f / 65536.0f);
    }
}

extern "C" void kernel_launch(void* const* d_in, const int* in_sizes, int n_in,
                              void* d_out, int out_size, void* d_ws, size_t ws_size,
                              hipStream_t stream) {
    const float* preds = (const float*)d_in[0];   // [8, 8192, 3]
    const float* gts   = (const float*)d_in[1];   // [8, 8192, 3]
    float* out = (float*)d_out;

    float* rowmin = (float*)d_ws;   // 2*8*8192 floats = 512 KB, fully overwritten
    float* bsums  = (float*)((char*)d_ws + (size_t)2 * BATCH * NPTS * sizeof(float));

    chamfer_mfma_kernel<<<512, TPB, 0, stream>>>(preds, gts, rowmin);
    chamfer_reduce1<<<512, 256, 0, stream>>>(rowmin, bsums);
    chamfer_reduce2<<<1, 512, 0, stream>>>(bsums, out);
}

// Round 5
// 45.833 us; speedup vs baseline: 2.1529x; 1.0423x over previous
//
#include <hip/hip_runtime.h>
#include <hip/hip_bf16.h>

// Chamfer via MFMA: D_nm = |x_n - y_m|^2 as an augmented K=16 fp16-split GEMM.
//   a(x) = [xh0..2, xl0..2, xh0..2, 1, 1, xxh, xxl, 0,0,0]
//   b(y) = [-2yh0..2, -2yh0..2, -2yl0..2, yyh, yyl, 1, 1, 0,0,0]
// One v_mfma_f32_32x32x16_f16 = one 32x32 distance tile, fp32 accum.
// Two passes (rows=gts,cols=preds then swapped): only ROW-mins -> no atomics.
// R5: R4 structure (TPB=512, 16 waves/CU, colhalf split) but NO inline-asm
// min3 — nested fminf instead (clang may fuse to v_min3_f32 itself; R4's
// hand-asm min3 was the prime suspect for the absmax=4704 garbage).

typedef _Float16 f16x8 __attribute__((ext_vector_type(8)));
typedef float f32x16 __attribute__((ext_vector_type(16)));

#define NPTS 8192
#define BATCH 8
#define TPB 512
#define BN 512                      // rows per block (8 waves x 2 rowtiles x 32)
#define BM 1024                     // cols staged per LDS chunk
#define CPB 4                       // chunks per block (half the col space)
#define CTPC (BM / 32)              // 32 col-tiles per chunk
#define NQ_TOT (2 * BATCH * NPTS)   // 131072

__device__ __forceinline__ void cvt_split(float v, _Float16& h, _Float16& l) {
    h = (_Float16)v;
    l = (_Float16)(v - (float)h);
}

__global__ __launch_bounds__(TPB, 4) void chamfer_mfma_kernel(
    const float* __restrict__ preds, const float* __restrict__ gts,
    float* __restrict__ partial /* [2][BATCH][NPTS][2] */)
{
    __shared__ f16x8 ldsB[CTPC][2][32];   // 32 KB: [coltile][khalf][col]

    const int bid  = blockIdx.x;          // 512 blocks
    const int pass = bid >> 8;
    const int b       = (bid >> 5) & 7;
    const int rowblk  = (bid >> 1) & 15;  // 16 row-blocks (8192/512)
    const int colhalf = bid & 1;

    const float* __restrict__ Asrc = (pass == 0) ? gts : preds;
    const float* __restrict__ Bsrc = (pass == 0) ? preds : gts;
    const float* __restrict__ Ab = Asrc + (size_t)b * NPTS * 3;
    const float* __restrict__ Bb = Bsrc + (size_t)b * NPTS * 3;

    const int tid  = threadIdx.x;
    const int lane = tid & 63;
    const int w    = tid >> 6;        // 8 waves
    const int kh   = lane >> 5;       // k-half
    const int cl   = lane & 31;       // row (A) / col (B) within tile

    // --- A fragments (2 row-tiles per wave) ---
    f16x8 af[2];
#pragma unroll
    for (int t = 0; t < 2; ++t) {
        const int row = rowblk * BN + w * 64 + t * 32 + cl;
        const float* xp = Ab + (size_t)row * 3;
        const float x0 = xp[0], x1 = xp[1], x2 = xp[2];
        _Float16 h0, l0, h1, l1, h2, l2;
        cvt_split(x0, h0, l0); cvt_split(x1, h1, l1); cvt_split(x2, h2, l2);
        const float xx = x0 * x0 + x1 * x1 + x2 * x2;
        _Float16 xxh, xxl; cvt_split(xx, xxh, xxl);
        const f16x8 lo = { h0, h1, h2, l0, l1, l2, h0, h1 };
        const f16x8 hi = { h2, (_Float16)1, (_Float16)1, xxh, xxl,
                           (_Float16)0, (_Float16)0, (_Float16)0 };
        af[t] = kh ? hi : lo;
    }

    const f16x8* __restrict__ bptr = &ldsB[0][kh][cl];
    const f32x16 zc = {};

    float rb[2][16];
#pragma unroll
    for (int t = 0; t < 2; ++t)
#pragma unroll
        for (int r = 0; r < 16; ++r) rb[t][r] = 1e30f;

    for (int chunk = 0; chunk < CPB; ++chunk) {
        const int cbase = (colhalf * CPB + chunk) * BM;
        __syncthreads();
        // --- stage+convert BM cols into LDS (2 points per thread) ---
#pragma unroll
        for (int i = 0; i < BM / TPB; ++i) {
            const int pl = i * TPB + tid;
            const float* yp = Bb + (size_t)(cbase + pl) * 3;
            const float y0 = yp[0], y1 = yp[1], y2 = yp[2];
            _Float16 nh0, nl0, nh1, nl1, nh2, nl2;
            { const float hf = (float)(_Float16)y0; nh0 = (_Float16)(-2.f * hf); nl0 = (_Float16)(-2.f * (y0 - hf)); }
            { const float hf = (float)(_Float16)y1; nh1 = (_Float16)(-2.f * hf); nl1 = (_Float16)(-2.f * (y1 - hf)); }
            { const float hf = (float)(_Float16)y2; nh2 = (_Float16)(-2.f * hf); nl2 = (_Float16)(-2.f * (y2 - hf)); }
            const float yy = y0 * y0 + y1 * y1 + y2 * y2;
            _Float16 yyh, yyl; cvt_split(yy, yyh, yyl);
            const f16x8 lo = { nh0, nh1, nh2, nh0, nh1, nh2, nl0, nl1 };
            const f16x8 hi = { nl2, yyh, yyl, (_Float16)1, (_Float16)1,
                               (_Float16)0, (_Float16)0, (_Float16)0 };
            ldsB[pl >> 5][0][pl & 31] = lo;
            ldsB[pl >> 5][1][pl & 31] = hi;
        }
        __syncthreads();

        // --- sweep col-tile PAIRS: 2 ds_read -> 4 MFMA -> min fold ---
#pragma unroll 2
        for (int ct = 0; ct < CTPC; ct += 2) {
            const f16x8 bfA = bptr[ct * 64];
            const f16x8 bfB = bptr[(ct + 1) * 64];
#pragma unroll
            for (int t = 0; t < 2; ++t) {
                const f32x16 aA = __builtin_amdgcn_mfma_f32_32x32x16_f16(af[t], bfA, zc, 0, 0, 0);
                const f32x16 aB = __builtin_amdgcn_mfma_f32_32x32x16_f16(af[t], bfB, zc, 0, 0, 0);
#pragma unroll
                for (int r = 0; r < 16; ++r)
                    rb[t][r] = fminf(fminf(aA[r], aB[r]), rb[t][r]);
            }
        }
    }

    // --- reduce row-mins across the 32 cols (lane bits 0..4) ---
#pragma unroll
    for (int t = 0; t < 2; ++t)
#pragma unroll
        for (int r = 0; r < 16; ++r) {
            float v = rb[t][r];
            v = fminf(v, __shfl_xor(v, 1, 64));
            v = fminf(v, __shfl_xor(v, 2, 64));
            v = fminf(v, __shfl_xor(v, 4, 64));
            v = fminf(v, __shfl_xor(v, 8, 64));
            v = fminf(v, __shfl_xor(v, 16, 64));
            rb[t][r] = v;
        }

    // C layout: col=lane&31, row=(r&3)+8*(r>>2)+4*(lane>>5)
    if (cl == 0) {
        float* rbase = partial + (((size_t)(pass * BATCH + b) * NPTS)
                     + rowblk * BN + w * 64) * 2 + colhalf;
#pragma unroll
        for (int t = 0; t < 2; ++t)
#pragma unroll
            for (int r = 0; r < 16; ++r) {
                const int rloc = (r & 3) + 8 * (r >> 2) + 4 * kh;
                rbase[(t * 32 + rloc) * 2] = rb[t][r];
            }
    }
}

// Stage 2: min the two col-half partials per query, sum -> 512 block sums
__global__ __launch_bounds__(256) void chamfer_reduce1(
    const float* __restrict__ partial, float* __restrict__ bsums)
{
    const int gid = blockIdx.x * 256 + threadIdx.x;   // one query per thread
    const float2 v = ((const float2*)partial)[gid];
    float m = fminf(v.x, v.y);

#pragma unroll
    for (int off = 32; off > 0; off >>= 1) m += __shfl_down(m, off, 64);

    __shared__ float wsum[4];
    const int lane = threadIdx.x & 63;
    const int wid  = threadIdx.x >> 6;
    if (lane == 0) wsum[wid] = m;
    __syncthreads();
    if (threadIdx.x == 0)
        bsums[blockIdx.x] = (wsum[0] + wsum[1]) + (wsum[2] + wsum[3]);
}

// Stage 3: sum 512 block sums, scale, write scalar
__global__ __launch_bounds__(512) void chamfer_reduce2(
    const float* __restrict__ bsums, float* __restrict__ out)
{
    float m = bsums[threadIdx.x];
#pragma unroll
    for (int off = 32; off > 0; off >>= 1) m += __shfl_down(m, off, 64);

    __shared__ float wsum[8];
    const int lane = threadIdx.x & 63;
    const int wid  = threadIdx.x >> 6;
    if (lane == 0) wsum[wid] = m;
    __syncthreads();
    if (threadIdx.x == 0) {
        float t = ((wsum[0] + wsum[1]) + (wsum[2] + wsum[3]))
                + ((wsum[4] + wsum[5]) + (wsum[6] + wsum[7]));
        out[0] = t * (1.0f / 65536.0f);
    }
}

extern "C" void kernel_launch(void* const* d_in, const int* in_sizes, int n_in,
                              void* d_out, int out_size, void* d_ws, size_t ws_size,
                              hipStream_t stream) {
    const float* preds = (const float*)d_in[0];   // [8, 8192, 3]
    const float* gts   = (const float*)d_in[1];   // [8, 8192, 3]
    float* out = (float*)d_out;

    float* partial = (float*)d_ws;   // 131072*2 floats = 1 MB, fully overwritten
    float* bsums   = (float*)((char*)d_ws + (size_t)NQ_TOT * 2 * sizeof(float));

    chamfer_mfma_kernel<<<512, TPB, 0, stream>>>(preds, gts, partial);
    chamfer_reduce1<<<512, 256, 0, stream>>>(partial, bsums);
    chamfer_reduce2<<<1, 512, 0, stream>>>(bsums, out);
}